// Round 5
// baseline (114.633 us; speedup 1.0000x reference)
//
#include <hip/hip_runtime.h>
#include <hip/hip_bf16.h>

// UnivariateFlowMixture: N=1e6 points, C=8 channels, L=8 layers, B=32 bins.
// Pipeline: build_tables (1 blk) -> grid_eval (marching, K=4 runs) ->
// interp (lerp + worklist compaction) -> exact_kernel (compacted fallback).
// Round 5: fixes round-4 workspace layout bug (tab is G*64 BYTES, not G*16).

#define TB 3.0f
#define NB 32
#define NC 8
#define NL 8
#define LN2 0.69314718055994530942f

#define GX0 -6.5f
#define GX1 6.5f
#define TZ 0.5f
#define TL 0.5f

#define PT_FLOATS (64 * 99)                  // 6336: 64 tables of 33|33|33
#define GP_FLOATS (PT_FLOATS + 72 + 72 + 8)  // + Sc | Bb | LJ  (6488 floats)
#define GP_BYTES  (GP_FLOATS * 4)            // 25952
#define CNT_OFF   GP_BYTES                   // 25952 (4-aligned)
#define TAB_OFF   (GP_BYTES + 16)            // 25968 = 16*1623 (16B-aligned)
#define K_RUN 4

__device__ __forceinline__ float softplusf(float v) {
    return fmaxf(v, 0.f) + log1pf(expf(-fabsf(v)));
}

__device__ __forceinline__ int bsearch32(const float* __restrict__ E, float xc) {
    int i = (xc >= E[16]) ? 16 : 0;
    i += (xc >= E[i + 8]) ? 8 : 0;
    i += (xc >= E[i + 4]) ? 4 : 0;
    i += (xc >= E[i + 2]) ? 2 : 0;
    i += (xc >= E[i + 1]) ? 1 : 0;
    return i;
}

// Tlc: [0..32] cumw edges, [33..65] cumh, [66..98] derivs (LDS or global)
__device__ __forceinline__ void spline_eval(const float* __restrict__ Tlc,
                                            float zc, float& zo, float& ldo) {
    const float* E  = Tlc;
    const float* Hc = Tlc + 33;
    const float* Dv = Tlc + 66;

    float xc = fminf(fmaxf(zc, -TB), TB);
    int i = bsearch32(E, xc);

    float xk  = E[i],  xk1 = E[i + 1];
    float yk  = Hc[i], yk1 = Hc[i + 1];
    float dk  = Dv[i], dk1 = Dv[i + 1];

    float wk    = xk1 - xk;
    float hk    = yk1 - yk;
    float invw  = __builtin_amdgcn_rcpf(wk);
    float delta = hk * invw;
    float th    = (xc - xk) * invw;
    float omt   = 1.f - th;
    float t1m   = th * omt;
    float th2   = th * th;

    float num    = hk * fmaf(delta, th2, dk * t1m);
    float den    = fmaf(fmaf(-2.f, delta, dk + dk1), t1m, delta);
    float invden = __builtin_amdgcn_rcpf(den);
    float y      = fmaf(num, invden, yk);

    float dt    = delta * t1m;
    float inner = fmaf(dk1, th2, fmaf(dk, omt * omt, dt + dt));
    float dnum  = (delta * delta) * inner;
    float r  = dnum * invden * invden;
    float ld = LN2 * __builtin_amdgcn_logf(r);

    bool inside = (zc >= -TB) && (zc <= TB);
    zo  = inside ? y : zc;
    ldo = inside ? ld : 0.f;
}

// ---------------- kernel 1: build tables once -> gparam ----------------
extern "C" __global__ void __launch_bounds__(256)
build_tables(const float* __restrict__ w, const float* __restrict__ h,
             const float* __restrict__ s, const float* __restrict__ bias,
             const float* __restrict__ lsc,
             float* __restrict__ gparam, unsigned* __restrict__ cnt)
{
    __shared__ float T[PT_FLOATS];
    __shared__ float Sc[72], Bb[72], LJ[8];

    const int tid = threadIdx.x;

    if (tid < 64) {                       // widths -> cumw edges
        const int l = tid >> 3, c = tid & 7;
        float* cw = &T[tid * 99];
        const float* wr = w + (l * NC + c) * NB;
        float m = wr[0];
        for (int b = 1; b < NB; ++b) m = fmaxf(m, wr[b]);
        float sum = 0.f;
        for (int b = 0; b < NB; ++b) sum += expf(wr[b] - m);
        float inv = 1.f / sum;
        float acc = 0.f;
        cw[0] = -TB;
        for (int b = 0; b < NB; ++b) {
            acc += 1e-3f + (1.f - 1e-3f * NB) * (expf(wr[b] - m) * inv);
            cw[b + 1] = 6.f * acc - 3.f;
        }
        cw[NB] = TB;
    } else if (tid < 128) {               // heights -> cumh
        const int t = tid - 64;
        const int l = t >> 3, c = t & 7;
        float* ch = &T[t * 99 + 33];
        const float* hr = h + (l * NC + c) * NB;
        float m = hr[0];
        for (int b = 1; b < NB; ++b) m = fmaxf(m, hr[b]);
        float sum = 0.f;
        for (int b = 0; b < NB; ++b) sum += expf(hr[b] - m);
        float inv = 1.f / sum;
        float acc = 0.f;
        ch[0] = -TB;
        for (int b = 0; b < NB; ++b) {
            acc += 1e-3f + (1.f - 1e-3f * NB) * (expf(hr[b] - m) * inv);
            ch[b + 1] = 6.f * acc - 3.f;
        }
        ch[NB] = TB;
    } else if (tid < 192) {               // derivs
        const int t = tid - 128;
        const int l = t >> 3, c = t & 7;
        float* dv = &T[t * 99 + 66];
        const float* sr = s + (l * NC + c) * (NB - 1);
        const float cst = logf(expm1f(1.f - 1e-3f));
        const float dbound = 1e-3f + softplusf(cst);
        dv[0]  = dbound;
        dv[NB] = dbound;
        for (int k = 0; k < NB - 1; ++k)
            dv[k + 1] = 1e-3f + softplusf(sr[k]);
    }
    if (tid < 72) { Sc[tid] = expf(-lsc[tid]); Bb[tid] = bias[tid]; }
    if (tid < 8) {
        float a = 0.f;
        for (int l = 0; l <= NL; ++l) a += lsc[l * NC + tid];
        LJ[tid] = -a;
    }
    if (tid == 0) *cnt = 0u;
    __syncthreads();

    for (int k = tid; k < PT_FLOATS; k += 256) gparam[k] = T[k];
    if (tid < 72) gparam[PT_FLOATS + tid]       = Sc[tid];
    if (tid < 72) gparam[PT_FLOATS + 72 + tid]  = Bb[tid];
    if (tid < 8)  gparam[PT_FLOATS + 144 + tid] = LJ[tid];
}

// ---------------- kernel 2: marching grid eval -> tab[G][C]{z,lj} ----------
extern "C" __global__ void __launch_bounds__(256)
grid_eval(const float* __restrict__ gparam, float* __restrict__ tab,
          int G, float dx)
{
    __shared__ float T[GP_FLOATS];
    for (int k = threadIdx.x; k < GP_FLOATS; k += 256) T[k] = gparam[k];
    __syncthreads();
    const float* ScT = T + PT_FLOATS;
    const float* BbT = ScT + 72;
    const float* LJT = BbT + 72;

    const int t  = blockIdx.x * 256 + threadIdx.x;
    const int c  = t & 7;
    const int i0 = (t >> 3) * K_RUN;
    if (i0 >= G) return;

    float scC[NL + 1], bbC[NL + 1];
#pragma unroll
    for (int l = 0; l <= NL; ++l) { scC[l] = ScT[l * 8 + c]; bbC[l] = BbT[l * 8 + c]; }
    const float ljc = LJT[c];

    int   bi[NL];
    float elo[NL], ehi[NL], yk[NL], hk[NL], dk[NL], dk1[NL], invw[NL];

#pragma unroll
    for (int p = 0; p < K_RUN; ++p) {
        const int i = i0 + p;
        float z  = fmaf((float)i, dx, GX0);
        float lj = ljc;
#pragma unroll
        for (int l = 0; l < NL; ++l) {
            const float* E = T + (l * 8 + c) * 99;
            const float u  = (z - bbC[l]) * scC[l];
            const float xc = fminf(fmaxf(u, -TB), TB);
            if (p == 0) {
                const int q = bsearch32(E, xc);
                bi[l]  = q;
                elo[l] = E[q]; ehi[l] = E[q + 1];
                yk[l]  = E[33 + q]; hk[l] = E[33 + q + 1] - yk[l];
                dk[l]  = E[66 + q]; dk1[l] = E[66 + q + 1];
                invw[l] = __builtin_amdgcn_rcpf(ehi[l] - elo[l]);
            } else {
                bool moved = false;
                while (bi[l] < NB - 1 && xc >= ehi[l]) {
                    elo[l] = ehi[l];
                    ++bi[l];
                    ehi[l] = E[bi[l] + 1];
                    moved = true;
                }
                if (moved) {
                    const int q = bi[l];
                    yk[l]  = E[33 + q]; hk[l] = E[33 + q + 1] - yk[l];
                    dk[l]  = E[66 + q]; dk1[l] = E[66 + q + 1];
                    invw[l] = __builtin_amdgcn_rcpf(ehi[l] - elo[l]);
                }
            }
            const float delta  = hk[l] * invw[l];
            const float th     = (xc - elo[l]) * invw[l];
            const float omt    = 1.f - th;
            const float t1m    = th * omt;
            const float th2    = th * th;
            const float num    = hk[l] * fmaf(delta, th2, dk[l] * t1m);
            const float den    = fmaf(fmaf(-2.f, delta, dk[l] + dk1[l]), t1m, delta);
            const float invden = __builtin_amdgcn_rcpf(den);
            const float y      = fmaf(num, invden, yk[l]);
            const float dt     = delta * t1m;
            const float inner  = fmaf(dk1[l], th2, fmaf(dk[l], omt * omt, dt + dt));
            const float r      = (delta * delta) * inner * invden * invden;
            const bool inside  = (u >= -TB) && (u <= TB);
            z  = inside ? y : u;
            lj += inside ? LN2 * __builtin_amdgcn_logf(r) : 0.f;
        }
        z = (z - bbC[NL]) * scC[NL];
        ((float2*)tab)[(size_t)i * NC + c] = make_float2(z, lj);
    }
}

// ---------------- kernel 3: interpolate + compact flagged points ------------
extern "C" __global__ void __launch_bounds__(256)
interp_kernel(const float* __restrict__ x, const float* __restrict__ tab,
              const float* __restrict__ gparam, float* __restrict__ out,
              unsigned* __restrict__ cnt, unsigned* __restrict__ wl, int wlcap,
              int N, int G, float dx, float invdx)
{
    const int n = blockIdx.x * 256 + threadIdx.x;
    if (n >= N) return;

    const float xv = x[n];
    int i = (int)floorf((xv - GX0) * invdx);
    const bool oor = !(xv > GX0 && xv < GX1);
    i = min(max(i, 0), G - 2);
    const float t = (xv - fmaf((float)i, dx, GX0)) * invdx;

    const float4* r0 = (const float4*)(tab + (size_t)i * (NC * 2));
    float4 a0 = r0[0], a1 = r0[1], a2 = r0[2], a3 = r0[3];
    float4 b0 = r0[4], b1 = r0[5], b2 = r0[6], b3 = r0[7];

    float z[NC], lj[NC];
    int flags = 0;
#define CH(cc, A, B, ZF, LF)                                            \
    { float dz = B.ZF - A.ZF, dl = B.LF - A.LF;                         \
      z[cc]  = fmaf(t, dz, A.ZF);                                       \
      lj[cc] = fmaf(t, dl, A.LF);                                       \
      if (fabsf(dz) > TZ || fabsf(dl) > TL) flags |= (1 << cc); }
    CH(0, a0, b0, x, y) CH(1, a0, b0, z, w)
    CH(2, a1, b1, x, y) CH(3, a1, b1, z, w)
    CH(4, a2, b2, x, y) CH(5, a2, b2, z, w)
    CH(6, a3, b3, x, y) CH(7, a3, b3, z, w)
#undef CH
    if (oor) flags = 0xff;

    if (flags) {
        const unsigned slot = atomicAdd(cnt, 1u);
        if (slot < (unsigned)wlcap) {
            wl[slot] = ((unsigned)n << 8) | (unsigned)flags;
        } else {
            // worklist overflow (shouldn't happen at sane caps): exact inline
            const float* ScG = gparam + PT_FLOATS;
            const float* BbG = ScG + 72;
            const float* LJG = BbG + 72;
#pragma unroll 1
            for (int c = 0; c < NC; ++c) {
                if (!((flags >> c) & 1)) continue;
                float zc = xv;
                float lacc = LJG[c];
#pragma unroll 1
                for (int l = 0; l < NL; ++l) {
                    zc = (zc - BbG[l * 8 + c]) * ScG[l * 8 + c];
                    float ld;
                    spline_eval(gparam + (l * 8 + c) * 99, zc, zc, ld);
                    lacc += ld;
                }
                z[c]  = (zc - BbG[NL * 8 + c]) * ScG[NL * 8 + c];
                lj[c] = lacc;
            }
        }
    }

    float4* oz = (float4*)(out + (size_t)n * NC);
    oz[0] = make_float4(z[0], z[1], z[2], z[3]);
    oz[1] = make_float4(z[4], z[5], z[6], z[7]);
    float4* ol = (float4*)(out + (size_t)N * NC + (size_t)n * NC);
    ol[0] = make_float4(lj[0], lj[1], lj[2], lj[3]);
    ol[1] = make_float4(lj[4], lj[5], lj[6], lj[7]);
}

// ---------------- kernel 4: exact pass over compacted worklist --------------
extern "C" __global__ void __launch_bounds__(256)
exact_kernel(const float* __restrict__ x, const float* __restrict__ gparam,
             const unsigned* __restrict__ cnt, const unsigned* __restrict__ wl,
             int wlcap, float* __restrict__ out, int N)
{
    const unsigned count = min(*cnt, (unsigned)wlcap);
    const unsigned base  = blockIdx.x * 256u;
    if (base >= count) return;            // uniform per block: safe pre-sync exit

    __shared__ float T[GP_FLOATS];
    for (int k = threadIdx.x; k < GP_FLOATS; k += 256) T[k] = gparam[k];
    __syncthreads();
    const float* ScT = T + PT_FLOATS;
    const float* BbT = ScT + 72;
    const float* LJT = BbT + 72;

    const unsigned total = gridDim.x * 256u;
    for (unsigned e = base + threadIdx.x; e < count; e += total) {
        const unsigned ent = wl[e];
        const int n     = (int)(ent >> 8);
        const int flags = (int)(ent & 0xffu);
        if (n >= N) continue;             // defensive: never write OOB
        const float xv  = x[n];
#pragma unroll 1
        for (int c = 0; c < NC; ++c) {
            if (!((flags >> c) & 1)) continue;
            float zc = xv;
            float lacc = LJT[c];
#pragma unroll 1
            for (int l = 0; l < NL; ++l) {
                zc = (zc - BbT[l * 8 + c]) * ScT[l * 8 + c];
                float ld;
                spline_eval(T + (l * 8 + c) * 99, zc, zc, ld);
                lacc += ld;
            }
            zc = (zc - BbT[NL * 8 + c]) * ScT[NL * 8 + c];
            out[(size_t)n * NC + c] = zc;
            out[(size_t)N * NC + (size_t)n * NC + c] = lacc;
        }
    }
}

// ---------------- legacy monolithic kernel (ws-too-small fallback) ----------
extern "C" __global__ void __launch_bounds__(256)
flow_kernel(const float* __restrict__ x, const float* __restrict__ w,
            const float* __restrict__ h, const float* __restrict__ s,
            const float* __restrict__ bias, const float* __restrict__ lsc,
            float* __restrict__ out, int N)
{
    __shared__ float T[PT_FLOATS];
    __shared__ float Bb[NL + 1][NC];
    __shared__ float Sc[NL + 1][NC];
    __shared__ float LJC[NC];

    const int tid = threadIdx.x;
    if (tid < 64) {
        const int l = tid >> 3, c = tid & 7;
        float* cw = &T[tid * 99];
        {
            const float* wr = w + (l * NC + c) * NB;
            float m = wr[0];
            for (int b = 1; b < NB; ++b) m = fmaxf(m, wr[b]);
            float sum = 0.f;
            for (int b = 0; b < NB; ++b) sum += expf(wr[b] - m);
            float inv = 1.f / sum;
            float acc = 0.f;
            cw[0] = -TB;
            for (int b = 0; b < NB; ++b) {
                acc += 1e-3f + (1.f - 1e-3f * NB) * (expf(wr[b] - m) * inv);
                cw[b + 1] = 6.f * acc - 3.f;
            }
            cw[NB] = TB;
        }
        {
            float* ch = cw + 33;
            const float* hr = h + (l * NC + c) * NB;
            float m = hr[0];
            for (int b = 1; b < NB; ++b) m = fmaxf(m, hr[b]);
            float sum = 0.f;
            for (int b = 0; b < NB; ++b) sum += expf(hr[b] - m);
            float inv = 1.f / sum;
            float acc = 0.f;
            ch[0] = -TB;
            for (int b = 0; b < NB; ++b) {
                acc += 1e-3f + (1.f - 1e-3f * NB) * (expf(hr[b] - m) * inv);
                ch[b + 1] = 6.f * acc - 3.f;
            }
            ch[NB] = TB;
        }
        {
            float* dv = cw + 66;
            const float* sr = s + (l * NC + c) * (NB - 1);
            const float cst = logf(expm1f(1.f - 1e-3f));
            const float dbound = 1e-3f + softplusf(cst);
            dv[0]  = dbound;
            dv[NB] = dbound;
            for (int k = 0; k < NB - 1; ++k)
                dv[k + 1] = 1e-3f + softplusf(sr[k]);
        }
    }
    if (tid < (NL + 1) * NC) {
        const int l = tid >> 3, c = tid & 7;
        Bb[l][c] = bias[tid];
        Sc[l][c] = expf(-lsc[tid]);
    }
    if (tid < NC) {
        float a = 0.f;
        for (int l = 0; l <= NL; ++l) a += lsc[l * NC + tid];
        LJC[tid] = -a;
    }
    __syncthreads();

    const int n = blockIdx.x * 256 + tid;
    if (n >= N) return;
    const float xv = x[n];
    float z[NC], lj[NC];
#pragma unroll
    for (int c = 0; c < NC; ++c) { z[c] = xv; lj[c] = LJC[c]; }
#pragma unroll 1
    for (int l = 0; l < NL; ++l) {
        const float* Tl = &T[l * NC * 99];
#pragma unroll
        for (int c = 0; c < NC; ++c) {
            float zc = (z[c] - Bb[l][c]) * Sc[l][c];
            float zo, ld;
            spline_eval(Tl + c * 99, zc, zo, ld);
            z[c] = zo;
            lj[c] += ld;
        }
    }
#pragma unroll
    for (int c = 0; c < NC; ++c) z[c] = (z[c] - Bb[NL][c]) * Sc[NL][c];

    float4* oz = (float4*)(out + (size_t)n * NC);
    oz[0] = make_float4(z[0], z[1], z[2], z[3]);
    oz[1] = make_float4(z[4], z[5], z[6], z[7]);
    float4* ol = (float4*)(out + (size_t)N * NC + (size_t)n * NC);
    ol[0] = make_float4(lj[0], lj[1], lj[2], lj[3]);
    ol[1] = make_float4(lj[4], lj[5], lj[6], lj[7]);
}

extern "C" void kernel_launch(void* const* d_in, const int* in_sizes, int n_in,
                              void* d_out, int out_size, void* d_ws, size_t ws_size,
                              hipStream_t stream) {
    const float* x    = (const float*)d_in[0];
    const float* w    = (const float*)d_in[1];
    const float* h    = (const float*)d_in[2];
    const float* s    = (const float*)d_in[3];
    const float* bias = (const float*)d_in[4];
    const float* lsc  = (const float*)d_in[5];
    float* out = (float*)d_out;
    const int N = in_sizes[0];

    // Layout (bytes): [0, GP_BYTES) gparam | [CNT_OFF, +16) cnt |
    //                 [TAB_OFF, +G*64) tab | [.., end) worklist
    const int minWL = 8192;
    int G = 65536;
    while (G > 2048 &&
           ((size_t)TAB_OFF + (size_t)G * 64 + (size_t)minWL * 4) > ws_size)
        G >>= 1;
    const size_t tabEnd = (size_t)TAB_OFF + (size_t)G * 64;
    const size_t need   = tabEnd + (size_t)minWL * 4;

    if (need <= ws_size) {
        char* basep = (char*)d_ws;
        float*    gparam = (float*)basep;
        unsigned* cnt    = (unsigned*)(basep + CNT_OFF);
        float*    tab    = (float*)(basep + TAB_OFF);
        unsigned* wl     = (unsigned*)(basep + tabEnd);
        long long capll  = (long long)((ws_size - tabEnd) / 4);
        int wlcap = (int)((capll > N) ? N : capll);

        const float dx = (GX1 - GX0) / (float)(G - 1);
        build_tables<<<1, 256, 0, stream>>>(w, h, s, bias, lsc, gparam, cnt);
        grid_eval<<<(G / K_RUN * NC + 255) / 256, 256, 0, stream>>>(gparam, tab, G, dx);
        interp_kernel<<<(N + 255) / 256, 256, 0, stream>>>(
            x, tab, gparam, out, cnt, wl, wlcap, N, G, dx, 1.f / dx);
        exact_kernel<<<64, 256, 0, stream>>>(x, gparam, cnt, wl, wlcap, out, N);
    } else {
        flow_kernel<<<(N + 255) / 256, 256, 0, stream>>>(
            x, w, h, s, bias, lsc, out, N);
    }
}

// Round 6
// 82.046 us; speedup vs baseline: 1.3972x; 1.3972x over previous
//
#include <hip/hip_runtime.h>
#include <hip/hip_bf16.h>

// UnivariateFlowMixture: N=1e6 points, C=8 channels, L=8 layers, B=32 bins.
// Pipeline: build_tables (1 blk) -> grid_eval (marching, packed f16 rows) ->
// interp (1-cache-line lerp + worklist compaction) -> exact (per entry-channel).
// Round 6: f16-packed single-line tab rows {z0,dz,lj0,dlj}x8ch, G up to 128K,
// exact_kernel parallelized per (entry,channel).

#define TB 3.0f
#define NB 32
#define NC 8
#define NL 8
#define LN2 0.69314718055994530942f

#define GX0 -6.5f
#define GX1 6.5f
#define TZ 0.5f
#define TL 0.5f

#define PT_FLOATS (64 * 99)                  // 6336: 64 tables of 33|33|33
#define GP_FLOATS (PT_FLOATS + 72 + 72 + 8)  // + Sc | Bb | LJ  (6488 floats)
#define GP_BYTES  (GP_FLOATS * 4)            // 25952
#define CNT_OFF   GP_BYTES                   // 25952 (4-aligned)
#define TAB_OFF   26112                      // 64B-aligned row base
#define K_RUN 4

__device__ __forceinline__ float softplusf(float v) {
    return fmaxf(v, 0.f) + log1pf(expf(-fabsf(v)));
}

__device__ __forceinline__ unsigned short f2h(float f) {
    _Float16 h = (_Float16)f;
    unsigned short u;
    __builtin_memcpy(&u, &h, 2);
    return u;
}
__device__ __forceinline__ float h2f(unsigned short u) {
    _Float16 h;
    __builtin_memcpy(&h, &u, 2);
    return (float)h;
}

__device__ __forceinline__ int bsearch32(const float* __restrict__ E, float xc) {
    int i = (xc >= E[16]) ? 16 : 0;
    i += (xc >= E[i + 8]) ? 8 : 0;
    i += (xc >= E[i + 4]) ? 4 : 0;
    i += (xc >= E[i + 2]) ? 2 : 0;
    i += (xc >= E[i + 1]) ? 1 : 0;
    return i;
}

// Tlc: [0..32] cumw edges, [33..65] cumh, [66..98] derivs (LDS or global)
__device__ __forceinline__ void spline_eval(const float* __restrict__ Tlc,
                                            float zc, float& zo, float& ldo) {
    const float* E  = Tlc;
    const float* Hc = Tlc + 33;
    const float* Dv = Tlc + 66;

    float xc = fminf(fmaxf(zc, -TB), TB);
    int i = bsearch32(E, xc);

    float xk  = E[i],  xk1 = E[i + 1];
    float yk  = Hc[i], yk1 = Hc[i + 1];
    float dk  = Dv[i], dk1 = Dv[i + 1];

    float wk    = xk1 - xk;
    float hk    = yk1 - yk;
    float invw  = __builtin_amdgcn_rcpf(wk);
    float delta = hk * invw;
    float th    = (xc - xk) * invw;
    float omt   = 1.f - th;
    float t1m   = th * omt;
    float th2   = th * th;

    float num    = hk * fmaf(delta, th2, dk * t1m);
    float den    = fmaf(fmaf(-2.f, delta, dk + dk1), t1m, delta);
    float invden = __builtin_amdgcn_rcpf(den);
    float y      = fmaf(num, invden, yk);

    float dt    = delta * t1m;
    float inner = fmaf(dk1, th2, fmaf(dk, omt * omt, dt + dt));
    float dnum  = (delta * delta) * inner;
    float r  = dnum * invden * invden;
    float ld = LN2 * __builtin_amdgcn_logf(r);

    bool inside = (zc >= -TB) && (zc <= TB);
    zo  = inside ? y : zc;
    ldo = inside ? ld : 0.f;
}

// ---------------- kernel 1: build tables once -> gparam ----------------
extern "C" __global__ void __launch_bounds__(256)
build_tables(const float* __restrict__ w, const float* __restrict__ h,
             const float* __restrict__ s, const float* __restrict__ bias,
             const float* __restrict__ lsc,
             float* __restrict__ gparam, unsigned* __restrict__ cnt)
{
    __shared__ float T[PT_FLOATS];
    __shared__ float Sc[72], Bb[72], LJ[8];

    const int tid = threadIdx.x;

    if (tid < 64) {                       // widths -> cumw edges
        const int l = tid >> 3, c = tid & 7;
        float* cw = &T[tid * 99];
        const float* wr = w + (l * NC + c) * NB;
        float m = wr[0];
        for (int b = 1; b < NB; ++b) m = fmaxf(m, wr[b]);
        float sum = 0.f;
        for (int b = 0; b < NB; ++b) sum += expf(wr[b] - m);
        float inv = 1.f / sum;
        float acc = 0.f;
        cw[0] = -TB;
        for (int b = 0; b < NB; ++b) {
            acc += 1e-3f + (1.f - 1e-3f * NB) * (expf(wr[b] - m) * inv);
            cw[b + 1] = 6.f * acc - 3.f;
        }
        cw[NB] = TB;
    } else if (tid < 128) {               // heights -> cumh
        const int t = tid - 64;
        float* ch = &T[t * 99 + 33];
        const int l = t >> 3, c = t & 7;
        const float* hr = h + (l * NC + c) * NB;
        float m = hr[0];
        for (int b = 1; b < NB; ++b) m = fmaxf(m, hr[b]);
        float sum = 0.f;
        for (int b = 0; b < NB; ++b) sum += expf(hr[b] - m);
        float inv = 1.f / sum;
        float acc = 0.f;
        ch[0] = -TB;
        for (int b = 0; b < NB; ++b) {
            acc += 1e-3f + (1.f - 1e-3f * NB) * (expf(hr[b] - m) * inv);
            ch[b + 1] = 6.f * acc - 3.f;
        }
        ch[NB] = TB;
    } else if (tid < 192) {               // derivs
        const int t = tid - 128;
        const int l = t >> 3, c = t & 7;
        float* dv = &T[t * 99 + 66];
        const float* sr = s + (l * NC + c) * (NB - 1);
        const float cst = logf(expm1f(1.f - 1e-3f));
        const float dbound = 1e-3f + softplusf(cst);
        dv[0]  = dbound;
        dv[NB] = dbound;
        for (int k = 0; k < NB - 1; ++k)
            dv[k + 1] = 1e-3f + softplusf(sr[k]);
    }
    if (tid < 72) { Sc[tid] = expf(-lsc[tid]); Bb[tid] = bias[tid]; }
    if (tid < 8) {
        float a = 0.f;
        for (int l = 0; l <= NL; ++l) a += lsc[l * NC + tid];
        LJ[tid] = -a;
    }
    if (tid == 0) *cnt = 0u;
    __syncthreads();

    for (int k = tid; k < PT_FLOATS; k += 256) gparam[k] = T[k];
    if (tid < 72) gparam[PT_FLOATS + tid]       = Sc[tid];
    if (tid < 72) gparam[PT_FLOATS + 72 + tid]  = Bb[tid];
    if (tid < 8)  gparam[PT_FLOATS + 144 + tid] = LJ[tid];
}

// ------- kernel 2: marching grid eval -> packed rows tab[i] (64 B) ---------
// row i (i in [0, G-2]): per channel c at byte c*8: {h(z_i), h(z_{i+1}-z_i),
//                                                    h(lj_i), h(lj_{i+1}-lj_i)}
extern "C" __global__ void __launch_bounds__(256)
grid_eval(const float* __restrict__ gparam, char* __restrict__ tabb,
          int G, float dx)
{
    __shared__ float T[GP_FLOATS];
    for (int k = threadIdx.x; k < GP_FLOATS; k += 256) T[k] = gparam[k];
    __syncthreads();
    const float* ScT = T + PT_FLOATS;
    const float* BbT = ScT + 72;
    const float* LJT = BbT + 72;

    const int t  = blockIdx.x * 256 + threadIdx.x;
    const int c  = t & 7;
    const int r0 = (t >> 3) * K_RUN;
    if (r0 >= G - 1) return;
    const int rend = min(r0 + K_RUN, G - 1);   // rows [r0, rend)

    float scC[NL + 1], bbC[NL + 1];
#pragma unroll
    for (int l = 0; l <= NL; ++l) { scC[l] = ScT[l * 8 + c]; bbC[l] = BbT[l * 8 + c]; }
    const float ljc = LJT[c];

    int   bi[NL];
    float elo[NL], ehi[NL], yk[NL], hk[NL], dk[NL], dk1[NL], invw[NL];
    float zprev = 0.f, ljprev = 0.f;

#pragma unroll 1
    for (int i = r0; i <= rend; ++i) {
        float z  = fmaf((float)i, dx, GX0);
        float lj = ljc;
        const bool first = (i == r0);
#pragma unroll
        for (int l = 0; l < NL; ++l) {
            const float* E = T + (l * 8 + c) * 99;
            const float u  = (z - bbC[l]) * scC[l];
            const float xc = fminf(fmaxf(u, -TB), TB);
            if (first) {
                const int q = bsearch32(E, xc);
                bi[l]  = q;
                elo[l] = E[q]; ehi[l] = E[q + 1];
                yk[l]  = E[33 + q]; hk[l] = E[34 + q] - yk[l];
                dk[l]  = E[66 + q]; dk1[l] = E[67 + q];
                invw[l] = __builtin_amdgcn_rcpf(ehi[l] - elo[l]);
            } else {
                bool moved = false;
                while (bi[l] < NB - 1 && xc >= ehi[l]) {
                    elo[l] = ehi[l];
                    ++bi[l];
                    ehi[l] = E[bi[l] + 1];
                    moved = true;
                }
                if (moved) {
                    const int q = bi[l];
                    yk[l]  = E[33 + q]; hk[l] = E[34 + q] - yk[l];
                    dk[l]  = E[66 + q]; dk1[l] = E[67 + q];
                    invw[l] = __builtin_amdgcn_rcpf(ehi[l] - elo[l]);
                }
            }
            const float delta  = hk[l] * invw[l];
            const float th     = (xc - elo[l]) * invw[l];
            const float omt    = 1.f - th;
            const float t1m    = th * omt;
            const float th2    = th * th;
            const float num    = hk[l] * fmaf(delta, th2, dk[l] * t1m);
            const float den    = fmaf(fmaf(-2.f, delta, dk[l] + dk1[l]), t1m, delta);
            const float invden = __builtin_amdgcn_rcpf(den);
            const float y      = fmaf(num, invden, yk[l]);
            const float dt     = delta * t1m;
            const float inner  = fmaf(dk1[l], th2, fmaf(dk[l], omt * omt, dt + dt));
            const float r      = (delta * delta) * inner * invden * invden;
            const bool inside  = (u >= -TB) && (u <= TB);
            z  = inside ? y : u;
            lj += inside ? LN2 * __builtin_amdgcn_logf(r) : 0.f;
        }
        z = (z - bbC[NL]) * scC[NL];
        if (!first) {
            ushort4 v;
            v.x = f2h(zprev);  v.y = f2h(z - zprev);
            v.z = f2h(ljprev); v.w = f2h(lj - ljprev);
            *(ushort4*)(tabb + (size_t)(i - 1) * 64 + c * 8) = v;
        }
        zprev = z; ljprev = lj;
    }
}

// ---------------- kernel 3: interpolate + compact flagged points ------------
extern "C" __global__ void __launch_bounds__(256)
interp_kernel(const float* __restrict__ x, const char* __restrict__ tabb,
              const float* __restrict__ gparam, float* __restrict__ out,
              unsigned* __restrict__ cnt, unsigned* __restrict__ wl, int wlcap,
              int N, int G, float dx, float invdx)
{
    const int n = blockIdx.x * 256 + threadIdx.x;
    if (n >= N) return;

    const float xv = x[n];
    int i = (int)floorf((xv - GX0) * invdx);
    const bool oor = !(xv > GX0 && xv < GX1);
    i = min(max(i, 0), G - 2);
    const float t = (xv - fmaf((float)i, dx, GX0)) * invdx;

    const float4* rp = (const float4*)(tabb + (size_t)i * 64);
    union { float4 q[4]; unsigned int u[16]; } R;
    R.q[0] = rp[0]; R.q[1] = rp[1]; R.q[2] = rp[2]; R.q[3] = rp[3];

    float z[NC], lj[NC];
    int flags = 0;
#pragma unroll
    for (int c = 0; c < NC; ++c) {
        const unsigned a = R.u[2 * c], b = R.u[2 * c + 1];
        const float z0 = h2f((unsigned short)a);
        const float dz = h2f((unsigned short)(a >> 16));
        const float l0 = h2f((unsigned short)b);
        const float dl = h2f((unsigned short)(b >> 16));
        z[c]  = fmaf(t, dz, z0);
        lj[c] = fmaf(t, dl, l0);
        if (fabsf(dz) > TZ || fabsf(dl) > TL) flags |= (1 << c);
    }
    if (oor) flags = 0xff;

    if (flags) {
        const unsigned slot = atomicAdd(cnt, 1u);
        if (slot < (unsigned)wlcap) {
            wl[slot] = ((unsigned)n << 8) | (unsigned)flags;
        } else {
            // overflow (rare): exact inline from global tables
            const float* ScG = gparam + PT_FLOATS;
            const float* BbG = ScG + 72;
            const float* LJG = BbG + 72;
#pragma unroll 1
            for (int c = 0; c < NC; ++c) {
                if (!((flags >> c) & 1)) continue;
                float zc = xv;
                float lacc = LJG[c];
#pragma unroll 1
                for (int l = 0; l < NL; ++l) {
                    zc = (zc - BbG[l * 8 + c]) * ScG[l * 8 + c];
                    float ld;
                    spline_eval(gparam + (l * 8 + c) * 99, zc, zc, ld);
                    lacc += ld;
                }
                z[c]  = (zc - BbG[NL * 8 + c]) * ScG[NL * 8 + c];
                lj[c] = lacc;
            }
        }
    }

    float4* oz = (float4*)(out + (size_t)n * NC);
    oz[0] = make_float4(z[0], z[1], z[2], z[3]);
    oz[1] = make_float4(z[4], z[5], z[6], z[7]);
    float4* ol = (float4*)(out + (size_t)N * NC + (size_t)n * NC);
    ol[0] = make_float4(lj[0], lj[1], lj[2], lj[3]);
    ol[1] = make_float4(lj[4], lj[5], lj[6], lj[7]);
}

// -------- kernel 4: exact pass, one thread per (entry, channel) -------------
extern "C" __global__ void __launch_bounds__(256)
exact_kernel(const float* __restrict__ x, const float* __restrict__ gparam,
             const unsigned* __restrict__ cnt, const unsigned* __restrict__ wl,
             int wlcap, float* __restrict__ out, int N)
{
    __shared__ float T[GP_FLOATS];
    for (int k = threadIdx.x; k < GP_FLOATS; k += 256) T[k] = gparam[k];
    __syncthreads();
    const float* ScT = T + PT_FLOATS;
    const float* BbT = ScT + 72;
    const float* LJT = BbT + 72;

    const unsigned count  = min(*cnt, (unsigned)wlcap);
    const unsigned total  = count * 8u;
    const unsigned stride = gridDim.x * 256u;
    for (unsigned u = blockIdx.x * 256u + threadIdx.x; u < total; u += stride) {
        const unsigned e = u >> 3;
        const int      c = (int)(u & 7u);
        const unsigned ent = wl[e];
        if (!((ent >> c) & 1u)) continue;          // flags = low 8 bits
        const int n = (int)(ent >> 8);
        if (n >= N) continue;                      // defensive
        const float xv = x[n];
        float zc = xv;
        float lacc = LJT[c];
#pragma unroll 1
        for (int l = 0; l < NL; ++l) {
            zc = (zc - BbT[l * 8 + c]) * ScT[l * 8 + c];
            float ld;
            spline_eval(T + (l * 8 + c) * 99, zc, zc, ld);
            lacc += ld;
        }
        zc = (zc - BbT[NL * 8 + c]) * ScT[NL * 8 + c];
        out[(size_t)n * NC + c] = zc;
        out[(size_t)N * NC + (size_t)n * NC + c] = lacc;
    }
}

// ---------------- legacy monolithic kernel (ws-too-small fallback) ----------
extern "C" __global__ void __launch_bounds__(256)
flow_kernel(const float* __restrict__ x, const float* __restrict__ w,
            const float* __restrict__ h, const float* __restrict__ s,
            const float* __restrict__ bias, const float* __restrict__ lsc,
            float* __restrict__ out, int N)
{
    __shared__ float T[PT_FLOATS];
    __shared__ float Bb[NL + 1][NC];
    __shared__ float Sc[NL + 1][NC];
    __shared__ float LJC[NC];

    const int tid = threadIdx.x;
    if (tid < 64) {
        const int l = tid >> 3, c = tid & 7;
        float* cw = &T[tid * 99];
        {
            const float* wr = w + (l * NC + c) * NB;
            float m = wr[0];
            for (int b = 1; b < NB; ++b) m = fmaxf(m, wr[b]);
            float sum = 0.f;
            for (int b = 0; b < NB; ++b) sum += expf(wr[b] - m);
            float inv = 1.f / sum;
            float acc = 0.f;
            cw[0] = -TB;
            for (int b = 0; b < NB; ++b) {
                acc += 1e-3f + (1.f - 1e-3f * NB) * (expf(wr[b] - m) * inv);
                cw[b + 1] = 6.f * acc - 3.f;
            }
            cw[NB] = TB;
        }
        {
            float* ch = cw + 33;
            const float* hr = h + (l * NC + c) * NB;
            float m = hr[0];
            for (int b = 1; b < NB; ++b) m = fmaxf(m, hr[b]);
            float sum = 0.f;
            for (int b = 0; b < NB; ++b) sum += expf(hr[b] - m);
            float inv = 1.f / sum;
            float acc = 0.f;
            ch[0] = -TB;
            for (int b = 0; b < NB; ++b) {
                acc += 1e-3f + (1.f - 1e-3f * NB) * (expf(hr[b] - m) * inv);
                ch[b + 1] = 6.f * acc - 3.f;
            }
            ch[NB] = TB;
        }
        {
            float* dv = cw + 66;
            const float* sr = s + (l * NC + c) * (NB - 1);
            const float cst = logf(expm1f(1.f - 1e-3f));
            const float dbound = 1e-3f + softplusf(cst);
            dv[0]  = dbound;
            dv[NB] = dbound;
            for (int k = 0; k < NB - 1; ++k)
                dv[k + 1] = 1e-3f + softplusf(sr[k]);
        }
    }
    if (tid < (NL + 1) * NC) {
        const int l = tid >> 3, c = tid & 7;
        Bb[l][c] = bias[tid];
        Sc[l][c] = expf(-lsc[tid]);
    }
    if (tid < NC) {
        float a = 0.f;
        for (int l = 0; l <= NL; ++l) a += lsc[l * NC + tid];
        LJC[tid] = -a;
    }
    __syncthreads();

    const int n = blockIdx.x * 256 + tid;
    if (n >= N) return;
    const float xv = x[n];
    float z[NC], lj[NC];
#pragma unroll
    for (int c = 0; c < NC; ++c) { z[c] = xv; lj[c] = LJC[c]; }
#pragma unroll 1
    for (int l = 0; l < NL; ++l) {
        const float* Tl = &T[l * NC * 99];
#pragma unroll
        for (int c = 0; c < NC; ++c) {
            float zc = (z[c] - Bb[l][c]) * Sc[l][c];
            float zo, ld;
            spline_eval(Tl + c * 99, zc, zo, ld);
            z[c] = zo;
            lj[c] += ld;
        }
    }
#pragma unroll
    for (int c = 0; c < NC; ++c) z[c] = (z[c] - Bb[NL][c]) * Sc[NL][c];

    float4* oz = (float4*)(out + (size_t)n * NC);
    oz[0] = make_float4(z[0], z[1], z[2], z[3]);
    oz[1] = make_float4(z[4], z[5], z[6], z[7]);
    float4* ol = (float4*)(out + (size_t)N * NC + (size_t)n * NC);
    ol[0] = make_float4(lj[0], lj[1], lj[2], lj[3]);
    ol[1] = make_float4(lj[4], lj[5], lj[6], lj[7]);
}

extern "C" void kernel_launch(void* const* d_in, const int* in_sizes, int n_in,
                              void* d_out, int out_size, void* d_ws, size_t ws_size,
                              hipStream_t stream) {
    const float* x    = (const float*)d_in[0];
    const float* w    = (const float*)d_in[1];
    const float* h    = (const float*)d_in[2];
    const float* s    = (const float*)d_in[3];
    const float* bias = (const float*)d_in[4];
    const float* lsc  = (const float*)d_in[5];
    float* out = (float*)d_out;
    const int N = in_sizes[0];

    // Layout (bytes): [0, GP_BYTES) gparam | [CNT_OFF,+16) cnt |
    //                 [TAB_OFF, +G*64) packed tab | [.., end) worklist
    const int minWL = 8192;
    int G = 131072;
    while (G > 2048 &&
           ((size_t)TAB_OFF + (size_t)G * 64 + (size_t)minWL * 4) > ws_size)
        G >>= 1;
    const size_t tabEnd = (size_t)TAB_OFF + (size_t)G * 64;
    const size_t need   = tabEnd + (size_t)minWL * 4;

    if (need <= ws_size) {
        char* basep = (char*)d_ws;
        float*    gparam = (float*)basep;
        unsigned* cnt    = (unsigned*)(basep + CNT_OFF);
        char*     tabb   = basep + TAB_OFF;
        unsigned* wl     = (unsigned*)(basep + tabEnd);
        long long capll  = (long long)((ws_size - tabEnd) / 4);
        int wlcap = (int)((capll > N) ? N : capll);

        const float dx = (GX1 - GX0) / (float)(G - 1);
        const int nruns = (G - 1 + K_RUN - 1) / K_RUN;
        build_tables<<<1, 256, 0, stream>>>(w, h, s, bias, lsc, gparam, cnt);
        grid_eval<<<(nruns * NC + 255) / 256, 256, 0, stream>>>(gparam, tabb, G, dx);
        interp_kernel<<<(N + 255) / 256, 256, 0, stream>>>(
            x, tabb, gparam, out, cnt, wl, wlcap, N, G, dx, 1.f / dx);
        exact_kernel<<<256, 256, 0, stream>>>(x, gparam, cnt, wl, wlcap, out, N);
    } else {
        flow_kernel<<<(N + 255) / 256, 256, 0, stream>>>(
            x, w, h, s, bias, lsc, out, N);
    }
}